// Round 4
// baseline (646.312 us; speedup 1.0000x reference)
//
#include <hip/hip_runtime.h>
#include <hip/hip_bf16.h>

typedef __bf16 bf16_t;
typedef __bf16 bf16x8 __attribute__((ext_vector_type(8)));
typedef float  f32x4  __attribute__((ext_vector_type(4)));

constexpr int Bc = 2, Tc = 2048, Ec = 2048, Hc = 16, Dc = 128;
constexpr int Mtok = Bc * Tc;  // 4096

// load 8 consecutive elements as bf16x8, converting if the source is fp32
__device__ __forceinline__ bf16x8 load8(const float* p) {
    f32x4 a = *(const f32x4*)p;
    f32x4 b = *(const f32x4*)(p + 4);
    bf16x8 r;
    r[0] = (bf16_t)a[0]; r[1] = (bf16_t)a[1];
    r[2] = (bf16_t)a[2]; r[3] = (bf16_t)a[3];
    r[4] = (bf16_t)b[0]; r[5] = (bf16_t)b[1];
    r[6] = (bf16_t)b[2]; r[7] = (bf16_t)b[3];
    return r;
}
__device__ __forceinline__ bf16x8 load8(const bf16_t* p) {
    return *(const bf16x8*)p;
}

// ---------------------------------------------------------------------------
// GEMM: C[m][n] = sum_k A[m][k] * W[n][k] + bias[n]
// A: [M][K] row-major (fp32 or bf16), W: [N][K] fp32 (nn.Linear weight).
// MODE 0: out flat [M][N] ; MODE 1: out [B,H,T,D] from m=(b,t), n=(h,d).
// Register-staged LDS (m93-class): 128x128 tile, BK=32, 4 waves (2x2 of
// 64x64), plain [row][k] LDS layout, bf16 MFMA with fp32 accumulate.
// ---------------------------------------------------------------------------
template <int MODE, typename TA, typename TOUT>
__global__ __launch_bounds__(256) void gemm_bt(const TA* __restrict__ A,
                                               const float* __restrict__ W,
                                               const float* __restrict__ bias,
                                               TOUT* __restrict__ out,
                                               int M, int N, int K) {
    __shared__ __align__(16) bf16_t ldsA[128 * 32];
    __shared__ __align__(16) bf16_t ldsB[128 * 32];

    const int tid  = threadIdx.x;
    const int wave = tid >> 6;
    const int lane = tid & 63;
    const int g    = lane >> 4;   // 0..3 (quad)
    const int n16  = lane & 15;   // 0..15
    const int m0 = blockIdx.x * 128;
    const int n0 = blockIdx.y * 128;
    const int row_off = (wave >> 1) * 64;
    const int col_off = (wave & 1) * 64;

    f32x4 acc[4][4] = {};

    // slot s (0..511) holds row = s>>2, 16B-bf16-chunk = s&3 of the 128x32
    // tile. thread owns slots tid and tid+256.
    const int r0 = tid >> 2;      // 0..63
    const int cc = tid & 3;
    const TA*    pa0 = A + (size_t)(m0 + r0) * K + cc * 8;
    const TA*    pa1 = A + (size_t)(m0 + r0 + 64) * K + cc * 8;
    const float* pb0 = W + (size_t)(n0 + r0) * K + cc * 8;
    const float* pb1 = W + (size_t)(n0 + r0 + 64) * K + cc * 8;

    for (int k0 = 0; k0 < K; k0 += 32) {
        bf16x8 va0 = load8(pa0 + k0);
        bf16x8 va1 = load8(pa1 + k0);
        bf16x8 vb0 = load8(pb0 + k0);
        bf16x8 vb1 = load8(pb1 + k0);
        __syncthreads();  // prior tile's readers done
        *(bf16x8*)&ldsA[(size_t)tid * 8]         = va0;
        *(bf16x8*)&ldsA[(size_t)(256 + tid) * 8] = va1;
        *(bf16x8*)&ldsB[(size_t)tid * 8]         = vb0;
        *(bf16x8*)&ldsB[(size_t)(256 + tid) * 8] = vb1;
        __syncthreads();  // staging visible

        bf16x8 af[4], bfr[4];
#pragma unroll
        for (int mt = 0; mt < 4; ++mt)
            af[mt] = *(const bf16x8*)&ldsA[(row_off + mt * 16 + n16) * 32 + g * 8];
#pragma unroll
        for (int nt = 0; nt < 4; ++nt)
            bfr[nt] = *(const bf16x8*)&ldsB[(col_off + nt * 16 + n16) * 32 + g * 8];
#pragma unroll
        for (int mt = 0; mt < 4; ++mt)
#pragma unroll
            for (int nt = 0; nt < 4; ++nt)
                acc[mt][nt] = __builtin_amdgcn_mfma_f32_16x16x32_bf16(
                    af[mt], bfr[nt], acc[mt][nt], 0, 0, 0);
    }

    // C/D layout (m89-verified): col(n) = lane&15, row(m) = (lane>>4)*4 + reg
#pragma unroll
    for (int nt = 0; nt < 4; ++nt) {
        int n = n0 + col_off + nt * 16 + n16;
        float bn = bias[n];
#pragma unroll
        for (int mt = 0; mt < 4; ++mt) {
#pragma unroll
            for (int r = 0; r < 4; ++r) {
                int m = m0 + row_off + mt * 16 + g * 4 + r;
                float cv = acc[mt][nt][r] + bn;
                size_t idx;
                if (MODE == 0) {
                    idx = (size_t)m * N + n;
                } else {
                    int b = m >> 11, t = m & (Tc - 1);
                    int h = n >> 7, d = n & (Dc - 1);
                    idx = (((size_t)(b * Hc + h)) * Tc + t) * Dc + d;
                }
                out[idx] = (TOUT)cv;
            }
        }
    }
}

// ---------------------------------------------------------------------------
// RoPE in-place on q,k laid out [B,H,T,D] (bf16); positions 1-indexed (t+1).
// thread d in [0,64): angle = (t+1) * 10000^(-d/64); pairs (d, d+64).
// ---------------------------------------------------------------------------
__global__ void rope_kernel(bf16_t* __restrict__ q, bf16_t* __restrict__ k) {
    int row = blockIdx.x * 4 + (threadIdx.x >> 6);  // (b*H+h)*T + t
    int d   = threadIdx.x & 63;
    int t   = row & (Tc - 1);
    float theta = powf(10000.0f, -(float)d * (1.0f / 64.0f));
    float ang   = (float)(t + 1) * theta;
    float sv, cv;
    sincosf(ang, &sv, &cv);
    size_t base = (size_t)row * Dc;
    float q1 = (float)q[base + d], q2 = (float)q[base + d + 64];
    q[base + d]      = (bf16_t)(q1 * cv - q2 * sv);
    q[base + d + 64] = (bf16_t)(q2 * cv + q1 * sv);
    float k1 = (float)k[base + d], k2 = (float)k[base + d + 64];
    k[base + d]      = (bf16_t)(k1 * cv - k2 * sv);
    k[base + d + 64] = (bf16_t)(k2 * cv + k1 * sv);
}

// ---------------------------------------------------------------------------
// Transpose V per (b,h): [T][D] -> [D][T]  (bf16)
// ---------------------------------------------------------------------------
__global__ void transpose_v(const bf16_t* __restrict__ v, bf16_t* __restrict__ vt) {
    __shared__ bf16_t tile[32][33];
    int bh = blockIdx.z;
    int t0 = blockIdx.x * 32, d0 = blockIdx.y * 32;
    int tx = threadIdx.x & 31, ty = threadIdx.x >> 5;  // 32x8
    const bf16_t* src = v + (size_t)bh * Tc * Dc;
    bf16_t* dst = vt + (size_t)bh * Tc * Dc;
#pragma unroll
    for (int i = 0; i < 32; i += 8)
        tile[ty + i][tx] = src[(size_t)(t0 + ty + i) * Dc + d0 + tx];
    __syncthreads();
#pragma unroll
    for (int i = 0; i < 32; i += 8)
        dst[(size_t)(d0 + ty + i) * Tc + t0 + tx] = tile[tx][ty + i];
}

// ---------------------------------------------------------------------------
// Causal flash attention. q,k: [B,H,T,D] bf16 (post-RoPE), vt: [B,H,D,T] bf16.
// out: att [B,T,E] bf16. Block = 4 waves = 64 queries.
// ---------------------------------------------------------------------------
constexpr int KP = 128 + 8;  // k_lds row pitch (elements)
constexpr int VP = 64 + 8;   // v_lds row pitch
constexpr int PP = 64 + 8;   // p_lds row pitch

__global__ __launch_bounds__(256) void attn_kernel(const bf16_t* __restrict__ q,
                                                   const bf16_t* __restrict__ kmat,
                                                   const bf16_t* __restrict__ vt,
                                                   bf16_t* __restrict__ out) {
    __shared__ __align__(16) bf16_t k_lds[64 * KP];       // [key][d]
    __shared__ __align__(16) bf16_t v_lds[128 * VP];      // [d][key]
    __shared__ __align__(16) bf16_t p_lds[4 * 16 * PP];   // per-wave [q][key]

    const int tid  = threadIdx.x;
    const int wave = tid >> 6, lane = tid & 63;
    const int g = lane >> 4, n16 = lane & 15;
    const int qt = blockIdx.x, bh = blockIdx.y;
    const int q0 = qt * 64;
    const size_t base = (size_t)bh * Tc * Dc;

    // persistent Q fragments: A[m = n16][k = g*8 + kk*32 + j]
    bf16x8 qf[4];
    {
        const bf16_t* qp = q + base + (size_t)(q0 + wave * 16 + n16) * Dc + g * 8;
#pragma unroll
        for (int kk = 0; kk < 4; ++kk) qf[kk] = *(const bf16x8*)(qp + kk * 32);
    }

    float m_run[4], l_run[4];
#pragma unroll
    for (int r = 0; r < 4; ++r) { m_run[r] = -1e30f; l_run[r] = 0.0f; }
    f32x4 o_acc[8] = {};

    const float scale = 0.08838834764831845f;  // 1/sqrt(128)
    const int n_kt = qt + 1;

    for (int kt = 0; kt < n_kt; ++kt) {
        const int k0 = kt * 64;
        // stage K tile [64 keys][128 d]: 1024 16B chunks, 4 per thread
#pragma unroll
        for (int i = 0; i < 4; ++i) {
            int s = i * 256 + tid, key = s >> 4, c = s & 15;
            *(bf16x8*)&k_lds[key * KP + c * 8] =
                *(const bf16x8*)&kmat[base + (size_t)(k0 + key) * Dc + c * 8];
        }
        // stage V^T tile [128 d][64 keys]: 1024 chunks
#pragma unroll
        for (int i = 0; i < 4; ++i) {
            int s = i * 256 + tid, dd = s >> 3, c = s & 7;
            *(bf16x8*)&v_lds[dd * VP + c * 8] =
                *(const bf16x8*)&vt[base + (size_t)dd * Tc + k0 + c * 8];
        }
        __syncthreads();

        // S = Q K^T (per wave: 16 queries x 64 keys)
        f32x4 s_acc[4];
#pragma unroll
        for (int nt = 0; nt < 4; ++nt) {
            f32x4 a = {};
            int key = nt * 16 + n16;
#pragma unroll
            for (int kk = 0; kk < 4; ++kk) {
                bf16x8 kf = *(const bf16x8*)&k_lds[key * KP + kk * 32 + g * 8];
                a = __builtin_amdgcn_mfma_f32_16x16x32_bf16(qf[kk], kf, a, 0, 0, 0);
            }
            s_acc[nt] = a;
        }

        // scale + causal mask (C/D: col=key via n16, row=g*4+r)
#pragma unroll
        for (int nt = 0; nt < 4; ++nt) {
            int key = k0 + nt * 16 + n16;
#pragma unroll
            for (int r = 0; r < 4; ++r) {
                int qq = q0 + wave * 16 + g * 4 + r;
                float v = s_acc[nt][r] * scale;
                s_acc[nt][r] = (key <= qq) ? v : -1e30f;
            }
        }

        // online softmax; a row lives across the 16 lanes sharing quad g
        float alpha[4];
#pragma unroll
        for (int r = 0; r < 4; ++r) {
            float rm = fmaxf(fmaxf(s_acc[0][r], s_acc[1][r]),
                             fmaxf(s_acc[2][r], s_acc[3][r]));
            rm = fmaxf(rm, __shfl_xor(rm, 1, 16));
            rm = fmaxf(rm, __shfl_xor(rm, 2, 16));
            rm = fmaxf(rm, __shfl_xor(rm, 4, 16));
            rm = fmaxf(rm, __shfl_xor(rm, 8, 16));
            float m_new = fmaxf(m_run[r], rm);
            alpha[r] = __expf(m_run[r] - m_new);
            m_run[r] = m_new;
            float sum = 0.0f;
#pragma unroll
            for (int nt = 0; nt < 4; ++nt) {
                float p = __expf(s_acc[nt][r] - m_new);
                s_acc[nt][r] = p;
                sum += p;
            }
            sum += __shfl_xor(sum, 1, 16);
            sum += __shfl_xor(sum, 2, 16);
            sum += __shfl_xor(sum, 4, 16);
            sum += __shfl_xor(sum, 8, 16);
            l_run[r] = l_run[r] * alpha[r] + sum;
        }
#pragma unroll
        for (int dt = 0; dt < 8; ++dt)
#pragma unroll
            for (int r = 0; r < 4; ++r) o_acc[dt][r] *= alpha[r];

        // P (C/D layout) -> per-wave LDS [q][key], plain padded layout
        {
            bf16_t* pw = &p_lds[wave * 16 * PP];
#pragma unroll
            for (int nt = 0; nt < 4; ++nt) {
                int key = nt * 16 + n16;
#pragma unroll
                for (int r = 0; r < 4; ++r)
                    pw[(g * 4 + r) * PP + key] = (bf16_t)s_acc[nt][r];
            }
        }
        __syncthreads();

        // O += P V  (A = P[q][key], B = Vt[d][key]); 64 keys = 2 MFMA chunks
        bf16x8 pf[2];
#pragma unroll
        for (int kk = 0; kk < 2; ++kk)
            pf[kk] = *(const bf16x8*)&p_lds[wave * 16 * PP + n16 * PP +
                                            kk * 32 + g * 8];
#pragma unroll
        for (int dt = 0; dt < 8; ++dt) {
            int dd = dt * 16 + n16;
#pragma unroll
            for (int kk = 0; kk < 2; ++kk) {
                bf16x8 vf = *(const bf16x8*)&v_lds[dd * VP + kk * 32 + g * 8];
                o_acc[dt] = __builtin_amdgcn_mfma_f32_16x16x32_bf16(
                    pf[kk], vf, o_acc[dt], 0, 0, 0);
            }
        }
        __syncthreads();
    }

    // epilogue: O / l, write att [B,T,E] (bf16)
    const int b = bh >> 4, h = bh & 15;
    float inv_l[4];
#pragma unroll
    for (int r = 0; r < 4; ++r) inv_l[r] = 1.0f / l_run[r];
#pragma unroll
    for (int dt = 0; dt < 8; ++dt) {
        int d = dt * 16 + n16;
#pragma unroll
        for (int r = 0; r < 4; ++r) {
            int qq = q0 + wave * 16 + g * 4 + r;
            size_t idx = ((size_t)(b * Tc + qq)) * Ec + h * Dc + d;
            out[idx] = (bf16_t)(o_acc[dt][r] * inv_l[r]);
        }
    }
}

// ---------------------------------------------------------------------------
extern "C" void kernel_launch(void* const* d_in, const int* in_sizes, int n_in,
                              void* d_out, int out_size, void* d_ws, size_t ws_size,
                              hipStream_t stream) {
    // Reference dtypes are float32 -> inputs and output are fp32 storage.
    const float* x  = (const float*)d_in[0];
    const float* Wq = (const float*)d_in[1];
    const float* bq = (const float*)d_in[2];
    const float* Wk = (const float*)d_in[3];
    const float* bk = (const float*)d_in[4];
    const float* Wv = (const float*)d_in[5];
    const float* bv = (const float*)d_in[6];
    const float* Wo = (const float*)d_in[7];
    const float* bo = (const float*)d_in[8];
    float* out = (float*)d_out;

    char* ws = (char*)d_ws;
    const size_t sz = (size_t)Bc * Hc * Tc * Dc * sizeof(bf16_t);  // 16.78 MB
    bf16_t* q   = (bf16_t*)(ws);
    bf16_t* k   = (bf16_t*)(ws + sz);
    bf16_t* v   = (bf16_t*)(ws + 2 * sz);  // consumed by transpose, then reused
    bf16_t* vt  = (bf16_t*)(ws + 3 * sz);
    bf16_t* att = v;  // alias: safe, attn reads only q/k/vt

    dim3 ggrid(Mtok / 128, Ec / 128);  // 32 x 16
    gemm_bt<1, float, bf16_t><<<ggrid, 256, 0, stream>>>(x, Wq, bq, q, Mtok, Ec, Ec);
    gemm_bt<1, float, bf16_t><<<ggrid, 256, 0, stream>>>(x, Wk, bk, k, Mtok, Ec, Ec);
    gemm_bt<1, float, bf16_t><<<ggrid, 256, 0, stream>>>(x, Wv, bv, v, Mtok, Ec, Ec);
    rope_kernel<<<Bc * Hc * Tc / 4, 256, 0, stream>>>(q, k);
    transpose_v<<<dim3(Tc / 32, Dc / 32, Bc * Hc), 256, 0, stream>>>(v, vt);
    attn_kernel<<<dim3(Tc / 64, Bc * Hc), 256, 0, stream>>>(q, k, vt, att);
    gemm_bt<0, bf16_t, float><<<ggrid, 256, 0, stream>>>(att, Wo, bo, out, Mtok, Ec, Ec);
}